// Round 1
// 375.406 us; speedup vs baseline: 1.0857x; 1.0857x over previous
//
#include <hip/hip_runtime.h>
#include <hip/hip_bf16.h>
#include <cstddef>
#include <cstdint>

#define NEG_SLOPE 0.2f
#define LN_EPS 1e-5f

typedef __attribute__((ext_vector_type(8))) short bf16x8;
typedef __attribute__((ext_vector_type(4))) float f32x4;

__device__ __forceinline__ unsigned short f2bf(float f) {
    __hip_bfloat16 h = __float2bfloat16(f);
    return *reinterpret_cast<unsigned short*>(&h);
}
__device__ __forceinline__ float bf2f(unsigned short u) {
    return __uint_as_float(((unsigned)u) << 16);
}
__device__ __forceinline__ float lrelu_exp(float e) {
    e = (e >= 0.f) ? e : NEG_SLOPE * e;
    return expf(e);
}

// ---------------------------------------------------------------------------
// GAT projection via bf16 MFMA: h = x @ W_gat, stored bf16 (hb), plus per-head
// logits a_s/a_d (fp32, reduced from the fp32 accumulator before rounding).
// ---------------------------------------------------------------------------
__global__ __launch_bounds__(256, 3) void k_gat_projm(
    const float* __restrict__ x, const unsigned short* __restrict__ Wgt,
    const float* __restrict__ atts, const float* __restrict__ attd,
    unsigned short* __restrict__ hb, float* __restrict__ a_s,
    float* __restrict__ a_d, int nn)
{
    __shared__ __align__(16) unsigned short sx[64][136];   // 17.4 KB
    __shared__ __align__(16) unsigned short sw[128][136];  // 34.8 KB

    const int tid  = threadIdx.x;
    const int base = blockIdx.x * 64;
    const int lane = tid & 63;
    const int w    = tid >> 6;
    const int ln   = lane & 15;
    const int quad = lane >> 4;

    for (int i = tid; i < 2048; i += 256) {
        int row = i >> 4, c = i & 15;
        *(bf16x8*)&sw[row][c * 8] = *(const bf16x8*)(Wgt + row * 128 + c * 8);
    }
    for (int i = tid; i < 2048; i += 256) {
        int row = i >> 5, c = i & 31;
        float4 v = make_float4(0.f, 0.f, 0.f, 0.f);
        if (base + row < nn) v = ((const float4*)(x + (size_t)(base + row) * 128))[c];
        ushort4 o;
        o.x = f2bf(v.x); o.y = f2bf(v.y); o.z = f2bf(v.z); o.w = f2bf(v.w);
        *(ushort4*)&sx[row][c * 4] = o;
    }
    __syncthreads();

    bf16x8 a[4];
    #pragma unroll
    for (int ks = 0; ks < 4; ++ks)
        a[ks] = *(const bf16x8*)&sx[w * 16 + ln][ks * 32 + quad * 8];

    f32x4 acc[8];
    #pragma unroll
    for (int nt = 0; nt < 8; ++nt) acc[nt] = (f32x4){0.f, 0.f, 0.f, 0.f};

    #pragma unroll
    for (int nt = 0; nt < 8; ++nt)
        #pragma unroll
        for (int ks = 0; ks < 4; ++ks) {
            bf16x8 b = *(const bf16x8*)&sw[nt * 16 + ln][ks * 32 + quad * 8];
            acc[nt] = __builtin_amdgcn_mfma_f32_16x16x32_bf16(a[ks], b, acc[nt], 0, 0, 0);
        }

    #pragma unroll
    for (int nt = 0; nt < 8; ++nt) {
        float av = atts[nt * 16 + ln];
        float dv = attd[nt * 16 + ln];
        #pragma unroll
        for (int r = 0; r < 4; ++r) {
            int node = base + w * 16 + quad * 4 + r;
            float val = acc[nt][r];
            float ps = val * av, pd = val * dv;
            #pragma unroll
            for (int off = 1; off < 16; off <<= 1) {
                ps += __shfl_xor(ps, off, 16);
                pd += __shfl_xor(pd, off, 16);
            }
            if (node < nn) {
                hb[(size_t)node * 128 + nt * 16 + ln] = f2bf(val);
                if (ln == 0) {
                    a_s[(size_t)node * 8 + nt] = ps;
                    a_d[(size_t)node * 8 + nt] = pd;
                }
            }
        }
    }
}

// ---------------------------------------------------------------------------
// CSR binning: deg histogram -> two-level exclusive scan -> scatter.
// ---------------------------------------------------------------------------
__global__ __launch_bounds__(256) void k_deg(
    const int* __restrict__ ei, int* __restrict__ deg, int E)
{
    int e = blockIdx.x * 256 + threadIdx.x;
    if (e < E) atomicAdd(&deg[ei[(size_t)E + e]], 1);
}

__global__ __launch_bounds__(256) void k_scan_blk(
    const int* __restrict__ deg, int* __restrict__ bsum, int nn)
{
    __shared__ int ws[4];
    const int tid = threadIdx.x;
    const int base = blockIdx.x * 1024 + tid * 4;
    int4 v = make_int4(0, 0, 0, 0);
    if (base + 3 < nn) v = *(const int4*)(deg + base);
    else {
        if (base + 0 < nn) v.x = deg[base + 0];
        if (base + 1 < nn) v.y = deg[base + 1];
        if (base + 2 < nn) v.z = deg[base + 2];
    }
    int total = v.x + v.y + v.z + v.w;
    #pragma unroll
    for (int off = 32; off; off >>= 1) total += __shfl_xor(total, off, 64);
    if ((tid & 63) == 0) ws[tid >> 6] = total;
    __syncthreads();
    if (tid == 0) bsum[blockIdx.x] = ws[0] + ws[1] + ws[2] + ws[3];
}

__global__ __launch_bounds__(1024) void k_scan_top(int* __restrict__ bsum, int nblk)
{
    __shared__ int part[1024];
    const int tid = threadIdx.x;
    int v = (tid < nblk) ? bsum[tid] : 0;
    part[tid] = v;
    __syncthreads();
    for (int d = 1; d < 1024; d <<= 1) {
        int add = (tid >= d) ? part[tid - d] : 0;
        __syncthreads();
        part[tid] += add;
        __syncthreads();
    }
    if (tid < nblk) bsum[tid] = part[tid] - v;  // exclusive
}

__global__ __launch_bounds__(256) void k_scan_out(
    const int* __restrict__ deg, const int* __restrict__ bsum,
    int* __restrict__ ptr, int nn)
{
    __shared__ int ws[4];
    const int tid = threadIdx.x;
    const int lane = tid & 63;
    const int wid = tid >> 6;
    const int base = blockIdx.x * 1024 + tid * 4;
    int4 v = make_int4(0, 0, 0, 0);
    if (base + 3 < nn) v = *(const int4*)(deg + base);
    else {
        if (base + 0 < nn) v.x = deg[base + 0];
        if (base + 1 < nn) v.y = deg[base + 1];
        if (base + 2 < nn) v.z = deg[base + 2];
    }
    int t1 = v.x + v.y, t2 = t1 + v.z;
    int total = t2 + v.w;
    int inc = total;
    #pragma unroll
    for (int off = 1; off < 64; off <<= 1) {
        int y = __shfl_up(inc, off, 64);
        if (lane >= off) inc += y;
    }
    int wexcl = inc - total;
    if (lane == 63) ws[wid] = inc;
    __syncthreads();
    int woff = 0;
    #pragma unroll
    for (int i = 0; i < 4; ++i) if (i < wid) woff += ws[i];
    int e0 = bsum[blockIdx.x] + woff + wexcl;
    int4 o;
    o.x = e0; o.y = e0 + v.x; o.z = e0 + t1; o.w = e0 + t2;
    if (base + 3 < nn) *(int4*)(ptr + base) = o;
    else {
        if (base + 0 < nn) ptr[base + 0] = o.x;
        if (base + 1 < nn) ptr[base + 1] = o.y;
        if (base + 2 < nn) ptr[base + 2] = o.z;
    }
}

__global__ __launch_bounds__(256) void k_scatter(
    const int* __restrict__ ei, int* __restrict__ ptr,
    int* __restrict__ esrc, int E)
{
    int e = blockIdx.x * 256 + threadIdx.x;
    if (e < E) {
        int pos = atomicAdd(&ptr[ei[(size_t)E + e]], 1);
        esrc[pos] = ei[e];
    }
}

// ---------------------------------------------------------------------------
// Gather + softmax + self-loop + residual + LN1 fused. Half-wave per dst.
// ---------------------------------------------------------------------------
__global__ __launch_bounds__(256) void k_gather(
    const int* __restrict__ esrc, const int* __restrict__ ptr,
    const unsigned short* __restrict__ hb, const float* __restrict__ a_s,
    const float* __restrict__ a_d, const float* __restrict__ x,
    const float* __restrict__ bgat, const float* __restrict__ g1,
    const float* __restrict__ b1, unsigned short* __restrict__ h1b, int nn)
{
    int d = (blockIdx.x * 256 + threadIdx.x) >> 5;
    if (d >= nn) return;
    const int l = threadIdx.x & 31;
    const int head = l >> 2;

    const int start = (d == 0) ? 0 : ptr[d - 1];
    const int end = ptr[d];
    const float ad = a_d[(size_t)d * 8 + head];

    float4 acc = make_float4(0.f, 0.f, 0.f, 0.f);
    float wsum = 0.f;
    int e = start;
    for (; e + 4 <= end; e += 4) {
        int s0 = esrc[e + 0], s1 = esrc[e + 1], s2 = esrc[e + 2], s3 = esrc[e + 3];
        float as0 = a_s[(size_t)s0 * 8 + head];
        float as1 = a_s[(size_t)s1 * 8 + head];
        float as2 = a_s[(size_t)s2 * 8 + head];
        float as3 = a_s[(size_t)s3 * 8 + head];
        ushort4 h0 = *(const ushort4*)(hb + (size_t)s0 * 128 + 4 * l);
        ushort4 h1 = *(const ushort4*)(hb + (size_t)s1 * 128 + 4 * l);
        ushort4 h2 = *(const ushort4*)(hb + (size_t)s2 * 128 + 4 * l);
        ushort4 h3 = *(const ushort4*)(hb + (size_t)s3 * 128 + 4 * l);
        float w0 = lrelu_exp(as0 + ad);
        float w1 = lrelu_exp(as1 + ad);
        float w2 = lrelu_exp(as2 + ad);
        float w3 = lrelu_exp(as3 + ad);
        acc.x += w0 * bf2f(h0.x) + w1 * bf2f(h1.x) + w2 * bf2f(h2.x) + w3 * bf2f(h3.x);
        acc.y += w0 * bf2f(h0.y) + w1 * bf2f(h1.y) + w2 * bf2f(h2.y) + w3 * bf2f(h3.y);
        acc.z += w0 * bf2f(h0.z) + w1 * bf2f(h1.z) + w2 * bf2f(h2.z) + w3 * bf2f(h3.z);
        acc.w += w0 * bf2f(h0.w) + w1 * bf2f(h1.w) + w2 * bf2f(h2.w) + w3 * bf2f(h3.w);
        wsum += (w0 + w1) + (w2 + w3);
    }
    for (; e < end; ++e) {
        int s = esrc[e];
        float w = lrelu_exp(a_s[(size_t)s * 8 + head] + ad);
        ushort4 hv = *(const ushort4*)(hb + (size_t)s * 128 + 4 * l);
        acc.x += w * bf2f(hv.x); acc.y += w * bf2f(hv.y);
        acc.z += w * bf2f(hv.z); acc.w += w * bf2f(hv.w);
        wsum += w;
    }
    {   // self loop
        float w = lrelu_exp(a_s[(size_t)d * 8 + head] + ad);
        ushort4 hv = *(const ushort4*)(hb + (size_t)d * 128 + 4 * l);
        acc.x += w * bf2f(hv.x); acc.y += w * bf2f(hv.y);
        acc.z += w * bf2f(hv.z); acc.w += w * bf2f(hv.w);
        wsum += w;
    }
    const float inv_dn = 1.f / wsum;
    float4 xv = *(const float4*)(x + (size_t)d * 128 + 4 * l);
    float4 bg = *(const float4*)(bgat + 4 * l);
    float v0 = xv.x + acc.x * inv_dn + bg.x;
    float v1 = xv.y + acc.y * inv_dn + bg.y;
    float v2 = xv.z + acc.z * inv_dn + bg.z;
    float v3 = xv.w + acc.w * inv_dn + bg.w;

    float s = v0 + v1 + v2 + v3;
    #pragma unroll
    for (int off = 16; off; off >>= 1) s += __shfl_xor(s, off, 32);
    float mu = s * (1.f / 128.f);
    float d0 = v0 - mu, d1 = v1 - mu, d2 = v2 - mu, d3 = v3 - mu;
    float q = d0 * d0 + d1 * d1 + d2 * d2 + d3 * d3;
    #pragma unroll
    for (int off = 16; off; off >>= 1) q += __shfl_xor(q, off, 32);
    float inv = rsqrtf(q * (1.f / 128.f) + LN_EPS);

    float4 gv = ((const float4*)g1)[l];
    float4 bv = ((const float4*)b1)[l];
    ushort4 ob;
    ob.x = f2bf(d0 * inv * gv.x + bv.x);
    ob.y = f2bf(d1 * inv * gv.y + bv.y);
    ob.z = f2bf(d2 * inv * gv.z + bv.z);
    ob.w = f2bf(d3 * inv * gv.w + bv.w);
    ((ushort4*)(h1b + (size_t)d * 128))[l] = ob;
}

// ---------------------------------------------------------------------------
// Weight transpose + bf16 convert (B^T layouts for MFMA b-fragments).
// ---------------------------------------------------------------------------
__global__ __launch_bounds__(256) void k_cvt(
    const float* __restrict__ W1, const float* __restrict__ W2,
    const float* __restrict__ Wg,
    unsigned short* __restrict__ W1t, unsigned short* __restrict__ W2t,
    unsigned short* __restrict__ Wgt)
{
    int t = blockIdx.x * 256 + threadIdx.x;
    if (t < 512 * 128) {
        int n = t >> 7, k = t & 127;
        W1t[t] = f2bf(W1[(size_t)k * 512 + n]);
        int n2 = t >> 9, k2 = t & 511;
        W2t[t] = f2bf(W2[(size_t)k2 * 128 + n2]);
        if (t < 128 * 128) {
            int n3 = t >> 7, k3 = t & 127;
            Wgt[t] = f2bf(Wg[(size_t)k3 * 128 + n3]);
        }
    }
}

// ---------------------------------------------------------------------------
// Fully fused FF: out = LN2( relu(h1 @ W1 + b1) @ W2 + b2 + h1 ).
// The 512-wide hidden never touches HBM.
//
// Trick: ff1 is computed SWAPPED (t^T = W1^T @ h1^T):
//   A-frag = W1t rows (ffcol), B-frag = h1 rows loaded exactly like a normal
//   A-fragment. Result C-layout: col=ln -> node, row=quad*4+r -> ff, i.e.
//   each lane holds ff-slices of ITS OWN node (node = tile*16 + ln).
// ff2 is then computed STANDARD (out = t @ W2) using the MFMA k-permutation
// freedom: k-slot (quad, j) := ff = 32*ks + (j<4 ? 4*quad+j : 16+4*quad+j-4),
// which is exactly the registers acc1 holds (two adjacent 16-ff tiles) ->
// zero cross-lane movement. W2 is staged into LDS PRE-PERMUTED in the same
// k-order so its B-frag remains a single ds_read_b128.
//
// 4 chunks of 128 over the hidden dim; 32 KB W1-chunk + 32 KB W2-chunk in
// LDS (70 KB -> 2 blocks/CU); ff2 accumulator (64 VGPR) persists.
// 256 threads = 4 waves, 32 nodes/wave, 128 nodes/block.
// ---------------------------------------------------------------------------
__global__ __launch_bounds__(256, 2) void k_ffu(
    const unsigned short* __restrict__ h1b,
    const unsigned short* __restrict__ W1t,   // [512 ffcol][128 k]
    const unsigned short* __restrict__ W2t,   // [128 outcol][512 ff]
    const float* __restrict__ b1, const float* __restrict__ b2,
    const float* __restrict__ g2, const float* __restrict__ bln2,
    float* __restrict__ out, int nn)
{
    __shared__ __align__(16) unsigned short sw1[128][136];  // 34.8 KB W1 chunk
    __shared__ __align__(16) unsigned short sw2[128][136];  // 34.8 KB W2 chunk (k-permuted)

    const int tid  = threadIdx.x;
    const int base = blockIdx.x * 128;
    const int lane = tid & 63;
    const int w    = tid >> 6;        // 0..3 -> nodes base + w*32 .. +31
    const int ln   = lane & 15;
    const int quad = lane >> 4;

    // Persistent h1 fragments (B-operand of swapped ff1; same bits as an
    // A-fragment of h1): node = base + w*32 + mt*16 + ln.
    const bf16x8 zf = {0, 0, 0, 0, 0, 0, 0, 0};
    bf16x8 hfrag[2][4];
    #pragma unroll
    for (int mt = 0; mt < 2; ++mt) {
        int node = base + w * 32 + mt * 16 + ln;
        #pragma unroll
        for (int ks = 0; ks < 4; ++ks)
            hfrag[mt][ks] = (node < nn)
                ? *(const bf16x8*)(h1b + (size_t)node * 128 + ks * 32 + quad * 8)
                : zf;
    }

    f32x4 acc2[2][8];
    #pragma unroll
    for (int mt = 0; mt < 2; ++mt)
        #pragma unroll
        for (int nt = 0; nt < 8; ++nt)
            acc2[mt][nt] = (f32x4){0.f, 0.f, 0.f, 0.f};

    for (int c = 0; c < 4; ++c) {
        if (c) __syncthreads();   // previous chunk's LDS reads complete
        // stage W1 chunk: rows c*128..+127 of W1t, contiguous bf16x8
        for (int i = tid; i < 2048; i += 256) {
            int row = i >> 4, col = (i & 15) * 8;
            *(bf16x8*)&sw1[row][col] =
                *(const bf16x8*)(W1t + (size_t)(c * 128 + row) * 128 + col);
        }
        // stage W2 chunk, k-permuted: stored pos (ks, q, j) holds
        // ff = 32*ks + (j<4 ? 4*q+j : 16 + 4*q + j-4)
        for (int i = tid; i < 2048; i += 256) {
            int row = i >> 4, g = i & 15;
            int ks = g >> 2, q = g & 3;
            const unsigned short* src =
                W2t + (size_t)row * 512 + c * 128 + ks * 32 + q * 4;
            union { bf16x8 v; ushort4 u[2]; } tmp;
            tmp.u[0] = *(const ushort4*)(src);
            tmp.u[1] = *(const ushort4*)(src + 16);
            *(bf16x8*)&sw2[row][ks * 32 + q * 8] = tmp.v;
        }
        __syncthreads();

        // ---- ff1 (swapped): acc1[mt][f] -> t^T tile, col=ln(node), row=ff
        f32x4 acc1[2][8];
        #pragma unroll
        for (int mt = 0; mt < 2; ++mt)
            #pragma unroll
            for (int f = 0; f < 8; ++f)
                acc1[mt][f] = (f32x4){0.f, 0.f, 0.f, 0.f};

        #pragma unroll
        for (int f = 0; f < 8; ++f)
            #pragma unroll
            for (int ks = 0; ks < 4; ++ks) {
                bf16x8 a = *(const bf16x8*)&sw1[f * 16 + ln][ks * 32 + quad * 8];
                acc1[0][f] = __builtin_amdgcn_mfma_f32_16x16x32_bf16(a, hfrag[0][ks], acc1[0][f], 0, 0, 0);
                acc1[1][f] = __builtin_amdgcn_mfma_f32_16x16x32_bf16(a, hfrag[1][ks], acc1[1][f], 0, 0, 0);
            }

        // ---- bias + relu + cvt to bf16 A-frags (permuted k-order, in-lane)
        bf16x8 pt[2][4];
        #pragma unroll
        for (int ks = 0; ks < 4; ++ks) {
            float4 bLo = *(const float4*)(b1 + c * 128 + ks * 32 + quad * 4);
            float4 bHi = *(const float4*)(b1 + c * 128 + ks * 32 + 16 + quad * 4);
            #pragma unroll
            for (int mt = 0; mt < 2; ++mt) {
                union { bf16x8 v; unsigned short u[8]; } P;
                P.u[0] = f2bf(fmaxf(acc1[mt][2 * ks][0] + bLo.x, 0.f));
                P.u[1] = f2bf(fmaxf(acc1[mt][2 * ks][1] + bLo.y, 0.f));
                P.u[2] = f2bf(fmaxf(acc1[mt][2 * ks][2] + bLo.z, 0.f));
                P.u[3] = f2bf(fmaxf(acc1[mt][2 * ks][3] + bLo.w, 0.f));
                P.u[4] = f2bf(fmaxf(acc1[mt][2 * ks + 1][0] + bHi.x, 0.f));
                P.u[5] = f2bf(fmaxf(acc1[mt][2 * ks + 1][1] + bHi.y, 0.f));
                P.u[6] = f2bf(fmaxf(acc1[mt][2 * ks + 1][2] + bHi.z, 0.f));
                P.u[7] = f2bf(fmaxf(acc1[mt][2 * ks + 1][3] + bHi.w, 0.f));
                pt[mt][ks] = P.v;
            }
        }

        // ---- ff2 (standard): acc2 += t @ W2_chunk
        #pragma unroll
        for (int nt = 0; nt < 8; ++nt)
            #pragma unroll
            for (int ks = 0; ks < 4; ++ks) {
                bf16x8 b = *(const bf16x8*)&sw2[nt * 16 + ln][ks * 32 + quad * 8];
                acc2[0][nt] = __builtin_amdgcn_mfma_f32_16x16x32_bf16(pt[0][ks], b, acc2[0][nt], 0, 0, 0);
                acc2[1][nt] = __builtin_amdgcn_mfma_f32_16x16x32_bf16(pt[1][ks], b, acc2[1][nt], 0, 0, 0);
            }
    }

    // ---- epilogue: + b2 + residual(h1) -> LN2 -> out (same as old k_ff2f)
    float gv[8], bv[8], bb[8];
    #pragma unroll
    for (int nt = 0; nt < 8; ++nt) {
        int col = nt * 16 + ln;
        gv[nt] = g2[col]; bv[nt] = bln2[col]; bb[nt] = b2[col];
    }
    #pragma unroll
    for (int mt = 0; mt < 2; ++mt) {
        #pragma unroll
        for (int r = 0; r < 4; ++r) {
            int node = base + w * 32 + mt * 16 + quad * 4 + r;
            bool ok = node < nn;
            float v[8];
            #pragma unroll
            for (int nt = 0; nt < 8; ++nt) {
                int col = nt * 16 + ln;
                float res = ok ? bf2f(h1b[(size_t)node * 128 + col]) : 0.f;
                v[nt] = acc2[mt][nt][r] + bb[nt] + res;
            }
            float s = 0.f;
            #pragma unroll
            for (int nt = 0; nt < 8; ++nt) s += v[nt];
            #pragma unroll
            for (int off = 1; off < 16; off <<= 1) s += __shfl_xor(s, off, 16);
            float mu = s * (1.f / 128.f);
            float q = 0.f;
            #pragma unroll
            for (int nt = 0; nt < 8; ++nt) { float dd = v[nt] - mu; q += dd * dd; }
            #pragma unroll
            for (int off = 1; off < 16; off <<= 1) q += __shfl_xor(q, off, 16);
            float inv = rsqrtf(q * (1.f / 128.f) + LN_EPS);
            if (ok)
                #pragma unroll
                for (int nt = 0; nt < 8; ++nt) {
                    int col = nt * 16 + ln;
                    out[(size_t)node * 128 + col] = (v[nt] - mu) * inv * gv[nt] + bv[nt];
                }
        }
    }
}

// ---------------------------------------------------------------------------
extern "C" void kernel_launch(void* const* d_in, const int* in_sizes, int n_in,
                              void* d_out, int out_size, void* d_ws, size_t ws_size,
                              hipStream_t stream) {
    const float* x    = (const float*)d_in[0];
    const int*   ei   = (const int*)d_in[1];
    const float* Wg   = (const float*)d_in[2];
    const float* atts = (const float*)d_in[3];
    const float* attd = (const float*)d_in[4];
    const float* bgat = (const float*)d_in[5];
    const float* W1   = (const float*)d_in[6];
    const float* b1   = (const float*)d_in[7];
    const float* W2   = (const float*)d_in[8];
    const float* b2   = (const float*)d_in[9];
    const float* g1   = (const float*)d_in[10];
    const float* bln1 = (const float*)d_in[11];
    const float* g2   = (const float*)d_in[12];
    const float* bln2 = (const float*)d_in[13];
    float* out = (float*)d_out;

    const int nn = in_sizes[0] / 128;
    const int E  = in_sizes[1] / 2;
    const int nblk = (nn + 1023) / 1024;

    // workspace: W1t | W2t | Wgt | h1b | hb | a_s | a_d | deg | ptr | bsum | esrc
    uintptr_t pa = ((uintptr_t)d_ws + 15) & ~(uintptr_t)15;
    unsigned short* W1t = (unsigned short*)pa;
    unsigned short* W2t = W1t + 512 * 128;
    unsigned short* Wgt = W2t + 128 * 512;
    unsigned short* h1b = Wgt + 128 * 128;
    unsigned short* hb  = h1b + (size_t)nn * 128;
    float* a_s = (float*)(hb + (size_t)nn * 128);
    float* a_d = a_s + (size_t)nn * 8;
    int*   deg = (int*)(a_d + (size_t)nn * 8);
    int*   ptr = deg + nn;
    int*   bsum = ptr + nn;
    int*   esrc = bsum + 1024;

    hipMemsetAsync(deg, 0, (size_t)nn * sizeof(int), stream);

    k_cvt<<<dim3(256), dim3(256), 0, stream>>>(W1, W2, Wg, W1t, W2t, Wgt);
    k_gat_projm<<<dim3((nn + 63) / 64), dim3(256), 0, stream>>>(
        x, Wgt, atts, attd, hb, a_s, a_d, nn);
    k_deg<<<dim3((E + 255) / 256), dim3(256), 0, stream>>>(ei, deg, E);
    k_scan_blk<<<dim3(nblk), dim3(256), 0, stream>>>(deg, bsum, nn);
    k_scan_top<<<dim3(1), dim3(1024), 0, stream>>>(bsum, nblk);
    k_scan_out<<<dim3(nblk), dim3(256), 0, stream>>>(deg, bsum, ptr, nn);
    k_scatter<<<dim3((E + 255) / 256), dim3(256), 0, stream>>>(ei, ptr, esrc, E);
    k_gather<<<dim3((nn * 32 + 255) / 256), dim3(256), 0, stream>>>(
        esrc, ptr, hb, a_s, a_d, x, bgat, g1, bln1, h1b, nn);

    k_ffu<<<dim3((nn + 127) / 128), dim3(256), 0, stream>>>(
        h1b, W1t, W2t, b1, b2, g2, bln2, out, nn);
}